// Round 6
// baseline (531.015 us; speedup 1.0000x reference)
//
#include <hip/hip_runtime.h>

// Unfold (im2col): IN (4,64,224,224) f32, K=3x3, pad=1, stride=1, dil=1
// (reference nh=k+dil quirk -> output spatial 223x223)
// out[ch][pos], ch=(b*64+c)*9+i*3+j (2304 channels), pos=oh*223+ow (49729)
//   = x[b,c,oh+i-1,ow+j-1] (zero-padded)
//
// V6: clone the 6.3TB/s fill kernel's structure. Flat 16B-aligned quad
// indexing (no heads/tails), grid-stride 2048x256, PLAIN stores (every
// NT-store variant stalled at ~2.2TB/s effective; fill proves plain
// stores hit 6.3). Boundary handling is branch-free: vec4 + 1 scalar
// load always; row-cross via lane selects, padding via validity masks.
// Only channel-cross/OOB quads (<0.02%) take an exec-masked scalar path.

#define OW       223u
#define OSP      49729u      // 223*223
#define IW       224u
#define PLANE_IN 50176u      // 224*224
#define NQ       28643904u   // total float4 quads (114575616/4, exact)
#define NTH      524288u     // 2048 blocks * 256 threads

typedef float vf4 __attribute__((ext_vector_type(4)));
typedef vf4 vf4u __attribute__((aligned(4)));   // 4B-aligned vector view

__global__ __launch_bounds__(256) void unfold223_v6(
    const float* __restrict__ x, float* __restrict__ out)
{
    const unsigned t0 = blockIdx.x * 256u + threadIdx.x;

    for (unsigned tq = t0; tq < NQ; tq += NTH) {
        const unsigned n   = tq * 4u;           // flat output element index
        const unsigned ch  = n / OSP;           // magic-mul
        const unsigned pos = n - ch * OSP;
        const unsigned q   = ch / 9u;
        const unsigned r   = ch - q * 9u;
        const unsigned i   = r / 3u;
        const unsigned j   = r - i * 3u;
        const int im1 = (int)i - 1;
        const int jm1 = (int)j - 1;
        const int off = im1 * (int)IW + jm1;
        const unsigned oh0 = pos / OW;          // magic-mul
        const unsigned ow0 = pos - oh0 * OW;
        const int src0 = (int)pos + (int)oh0 + off;   // elem0 src within plane
        const float* __restrict__ xq = x + q * PLANE_IN;

        // rare path: quad crosses channel boundary, or vec-load would go OOB
        const bool epath = (pos >= OSP - 3u) | (src0 < 0) |
                           (src0 > (int)(PLANE_IN - 8u));
        vf4 res;
        if (!epath) {
            // fast path: 5 contiguous input floats cover all cases
            vf4 v4  = *reinterpret_cast<const vf4u*>(xq + src0);
            float s = xq[src0 + 4];
            const unsigned ca = OW - ow0;       // >=1; row-cross if <=3
            // element e source: src0 + e + (e>=ca); skip of +1 at row cross
            float v0 = v4[0];
            float v1 = (ca == 1u) ? v4[2] : v4[1];
            float v2 = (ca <= 2u) ? v4[3] : v4[2];
            float v3 = (ca <= 3u) ? s     : v4[3];
            // validity: only top pad (i==0, oh==0) or left pad (j==0, ow==0)
            const bool top  = (im1 < 0) & (oh0 == 0u);
            const bool left = (jm1 < 0);
            const bool b0 = (top)               | (left & (ow0 == 0u));
            const bool b1 = (top & (ca != 1u))  | (left & (ca == 1u));
            const bool b2 = (top & (ca >  2u))  | (left & (ca == 2u));
            const bool b3 = (top & (ca >  3u))  | (left & (ca == 3u));
            res[0] = b0 ? 0.0f : v0;
            res[1] = b1 ? 0.0f : v1;
            res[2] = b2 ? 0.0f : v2;
            res[3] = b3 ? 0.0f : v3;
        } else {
            // full per-element decode (channel-cross / OOB-adjacent quads)
#pragma unroll
            for (int e = 0; e < 4; ++e) {
                const unsigned m    = n + (unsigned)e;
                const unsigned ech  = m / OSP;
                const unsigned epos = m - ech * OSP;
                const unsigned eq   = ech / 9u;
                const unsigned er   = ech - eq * 9u;
                const unsigned ei   = er / 3u;
                const unsigned ej   = er - ei * 3u;
                const unsigned eoh  = epos / OW;
                const unsigned eow  = epos - eoh * OW;
                const int ih = (int)(eoh + ei) - 1;
                const int iw = (int)(eow + ej) - 1;
                const bool valid = ((unsigned)ih < 224u) && ((unsigned)iw < 224u);
                const unsigned idx = valid
                    ? (eq * PLANE_IN + (unsigned)ih * IW + (unsigned)iw) : 0u;
                const float val = x[idx];
                res[e] = valid ? val : 0.0f;
            }
        }
        *reinterpret_cast<vf4*>(out + n) = res;   // plain aligned dwordx4
    }
}

extern "C" void kernel_launch(void* const* d_in, const int* in_sizes, int n_in,
                              void* d_out, int out_size, void* d_ws, size_t ws_size,
                              hipStream_t stream)
{
    const float* x = (const float*)d_in[0];
    float* out = (float*)d_out;
    unfold223_v6<<<dim3(2048), dim3(256), 0, stream>>>(x, out);
}

// Round 7
// 499.213 us; speedup vs baseline: 1.0637x; 1.0637x over previous
//
#include <hip/hip_runtime.h>

// Unfold (im2col): IN (4,64,224,224) f32, K=3x3, pad=1, stride=1, dil=1
// (reference nh=k+dil quirk -> output spatial 223x223)
// out[ch][pos], ch=(b*64+c)*9+i*3+j (2304 channels), pos=oh*223+ow (49729)
//   = x[b,c,oh+i-1,ow+j-1] (zero-padded)
//
// V7: input-centric decomposition — read once, write 9. Each thread owns
// (plane q, row r, cols col0..col0+3): 6 overlapping dwordx4 loads (rows
// r-1,r,r+1) -> register swizzles -> 9 dwordx4 stores (one per channel).
// Logical read volume drops 9x vs all prior variants (the one never-ablated
// asymmetry vs the 6.3TB/s fill kernel). Geometry: 56 quads/row, quad 55
// overlap-writes col 219 with identical data => no tails, no row-cross.
// Pad only at top row (i=0,r=0) and left col (j=0,col=0) => two masks.

#define OW       223u
#define OSP      49729ull    // 223*223
#define IW       224u
#define PLANE_IN 50176u      // 224*224

typedef float vf4 __attribute__((ext_vector_type(4)));
typedef vf4 vf4u __attribute__((aligned(4)));   // 4B-aligned vector view

__global__ __launch_bounds__(448) void unfold223_v7(
    const float* __restrict__ x, float* __restrict__ out)
{
    const unsigned q    = blockIdx.y;           // plane b*64+c (0..255)
    const unsigned band = blockIdx.x;           // 0..27 (bands of 8 rows)
    const unsigned t    = threadIdx.x;          // 0..447
    const unsigned rr   = t / 56u;              // row within band (0..7)
    const unsigned k    = t - rr * 56u;         // quad within row (0..55)
    const unsigned r    = band * 8u + rr;       // output row
    if (r > 222u) return;                       // last band has 7 rows

    const unsigned col0  = (k == 55u) ? 219u : 4u * k;  // overlap last quad
    const bool     edge0 = (col0 == 0u);
    const unsigned co    = edge0 ? 0u : col0 - 1u;      // left-shifted load col
    const unsigned rm    = (r == 0u) ? 0u : r - 1u;     // clamped top row

    const float* __restrict__ xq = x + q * PLANE_IN;

    // 6 loads: rows rm, r, r+1; cols [co..co+3] and [col0+1..col0+4]
    const vf4 am = *reinterpret_cast<const vf4u*>(xq + rm * IW + co);
    const vf4 bm = *reinterpret_cast<const vf4u*>(xq + rm * IW + col0 + 1u);
    const vf4 a0 = *reinterpret_cast<const vf4u*>(xq + r  * IW + co);
    const vf4 b0 = *reinterpret_cast<const vf4u*>(xq + r  * IW + col0 + 1u);
    const vf4 ap = *reinterpret_cast<const vf4u*>(xq + (r + 1u) * IW + co);
    const vf4 bp = *reinterpret_cast<const vf4u*>(xq + (r + 1u) * IW + col0 + 1u);

    // Build the 3 column-shifted quads for one row pair (a,b):
    //  col0>0 : a=(c-1,c0,c1,c2), b=(c1,c2,c3,c4)
    //           j0=a  j1=(a1,a2,a3,b2)  j2=b
    //  col0==0: a=(c0,c1,c2,c3),  b=(c1,c2,c3,c4)
    //           j0=(0,a0,a1,a2)  j1=a  j2=b   (left pad)
#define TRIO(a, b, q0, q1, q2)                                     \
    vf4 q0, q1, q2;                                                \
    if (edge0) { q0 = (vf4){0.0f, a.x, a.y, a.z}; q1 = a; }        \
    else       { q0 = a; q1 = (vf4){a.y, a.z, a.w, b.z}; }         \
    q2 = b;

    TRIO(am, bm, t00, t01, t02)   // i=0 (reads row r-1)
    TRIO(a0, b0, t10, t11, t12)   // i=1
    TRIO(ap, bp, t20, t21, t22)   // i=2

    // top pad: i=0 channels are all-zero on output row 0
    if (r == 0u) {
        t00 = (vf4)0.0f; t01 = (vf4)0.0f; t02 = (vf4)0.0f;
    }

    float* __restrict__ och = out + (unsigned long long)q * 9ull * OSP;
    const unsigned rc = r * OW + col0;

    *reinterpret_cast<vf4u*>(och + 0ull * OSP + rc) = t00;
    *reinterpret_cast<vf4u*>(och + 1ull * OSP + rc) = t01;
    *reinterpret_cast<vf4u*>(och + 2ull * OSP + rc) = t02;
    *reinterpret_cast<vf4u*>(och + 3ull * OSP + rc) = t10;
    *reinterpret_cast<vf4u*>(och + 4ull * OSP + rc) = t11;
    *reinterpret_cast<vf4u*>(och + 5ull * OSP + rc) = t12;
    *reinterpret_cast<vf4u*>(och + 6ull * OSP + rc) = t20;
    *reinterpret_cast<vf4u*>(och + 7ull * OSP + rc) = t21;
    *reinterpret_cast<vf4u*>(och + 8ull * OSP + rc) = t22;
}

extern "C" void kernel_launch(void* const* d_in, const int* in_sizes, int n_in,
                              void* d_out, int out_size, void* d_ws, size_t ws_size,
                              hipStream_t stream)
{
    const float* x = (const float*)d_in[0];
    float* out = (float*)d_out;
    // 28 row-bands x 256 planes, 448 threads = 8 rows x 56 quads
    unfold223_v7<<<dim3(28, 256), dim3(448), 0, stream>>>(x, out);
}